// Round 1
// baseline (1991.464 us; speedup 1.0000x reference)
//
#include <hip/hip_runtime.h>
#include <math.h>

// B=256, T=2048, H=150. Sequential GRU, relu'd hidden, scalar linear head.
// 1 block / batch element (256 blocks = 256 CUs), 512 threads.
//
// R13 = R12's verified phase-1 (4-row/chain-split, op_sel-broadcast pk_fma,
// conflict-free b64 partial stores) with the h-distribution restructured:
//   - Phase 2 is computed REDUNDANTLY by every wave: lane l of chain-q wave
//     computes hidden unit u = 4l+q. Result: each wave ends phase-2 holding
//     exactly hq[m] = h[4m+q] in a live VGPR -- phase-1's readlane source.
//     No h4 LDS round trip (the old h4[lane] float4 read was 16B-stride =
//     the 6.1e7 bank conflicts AND ~150 serial cycles at every iter start).
//   - PPf double-buffered [2][2048] -> ONE barrier per iteration. phase2(t)
//     reads buf t&1 while phase1(t+1) writes buf (t+1)&1; barrier(t+1)
//     (after phase1(t+1)) fences phase2(t) reads against phase1(t+2).
//   - y-row (450) folded into the gate branch's load shadow: wave0/lane38
//     aliases ir->iy, bhh_r->b_lin, so y's LDS reads issue with the gate
//     reads instead of serially after them.
// Same operands, same ((q0+q1)+(q2+q3))+bhh tree, same per-unit gate math
// => bit-identical numerics to R12.

#define BB 256
#define TT 2048
#define HH 150
#define H3 450

typedef float fx2 __attribute__((ext_vector_type(2)));

// Clobber list for explicit weight registers v100..v251.
#define WCLOB \
  "v100","v101","v102","v103","v104","v105","v106","v107","v108","v109", \
  "v110","v111","v112","v113","v114","v115","v116","v117","v118","v119", \
  "v120","v121","v122","v123","v124","v125","v126","v127","v128","v129", \
  "v130","v131","v132","v133","v134","v135","v136","v137","v138","v139", \
  "v140","v141","v142","v143","v144","v145","v146","v147","v148","v149", \
  "v150","v151","v152","v153","v154","v155","v156","v157","v158","v159", \
  "v160","v161","v162","v163","v164","v165","v166","v167","v168","v169", \
  "v170","v171","v172","v173","v174","v175","v176","v177","v178","v179", \
  "v180","v181","v182","v183","v184","v185","v186","v187","v188","v189", \
  "v190","v191","v192","v193","v194","v195","v196","v197","v198","v199", \
  "v200","v201","v202","v203","v204","v205","v206","v207","v208","v209", \
  "v210","v211","v212","v213","v214","v215","v216","v217","v218","v219", \
  "v220","v221","v222","v223","v224","v225","v226","v227","v228","v229", \
  "v230","v231","v232","v233","v234","v235","v236","v237","v238","v239", \
  "v240","v241","v242","v243","v244","v245","v246","v247","v248","v249", \
  "v250","v251"

// Load one k-slot (offset OFF = 16*m bytes) for all 4 rows.
#define LD4(vA0,vA1,vB0,vB1,OFF) \
  "global_load_dword v" #vA0 ", %[b0], off offset:" #OFF "\n\t" \
  "global_load_dword v" #vA1 ", %[b1], off offset:" #OFF "\n\t" \
  "global_load_dword v" #vB0 ", %[b2], off offset:" #OFF "\n\t" \
  "global_load_dword v" #vB1 ", %[b3], off offset:" #OFF "\n\t"

// pk_fma with src0-low broadcast to both packed lanes.
#define PKB(sp, vp, acc) \
  "v_pk_fma_f32 " acc ", " sp ", " vp ", " acc " op_sel:[0,0,0] op_sel_hi:[0,1,1]\n\t"

// 4 k-elems: 4 readlanes (even SGPRs only) then 8 broadcast-pk_fmas.
// First consumer of s20 is 4 insts after its write.
#define G4(m0,m1,m2,m3, A0,B0, A1,B1, A2,B2, A3,B3) \
  "v_readlane_b32 s20, %[hq], " #m0 "\n\t" \
  "v_readlane_b32 s22, %[hq], " #m1 "\n\t" \
  "v_readlane_b32 s24, %[hq], " #m2 "\n\t" \
  "v_readlane_b32 s26, %[hq], " #m3 "\n\t" \
  PKB("s[20:21]", A0, "%[a01]") PKB("s[20:21]", B0, "%[a23]") \
  PKB("s[22:23]", A1, "%[a01]") PKB("s[22:23]", B1, "%[a23]") \
  PKB("s[24:25]", A2, "%[a01]") PKB("s[24:25]", B2, "%[a23]") \
  PKB("s[26:27]", A3, "%[a01]") PKB("s[26:27]", B3, "%[a23]")

__global__ __launch_bounds__(512, 2) void gru_seq_kernel(
    const float* __restrict__ input,   // [B,T]
    const float* __restrict__ W_ih,    // [450,1]
    const float* __restrict__ W_hh,    // [450,150]
    const float* __restrict__ b_ih,    // [450]
    const float* __restrict__ b_hh,    // [450]
    const float* __restrict__ W_lin,   // [1,150]
    const float* __restrict__ b_lin,   // [1]
    float* __restrict__ out)           // [B,T]
{
    const int b    = blockIdx.x;
    const int tid  = threadIdx.x;
    const int lane = tid & 63;
    const int wid  = tid >> 6;               // 0..7
    const int q    = wid & 3;                // wave-uniform chain/quarter
    const int idx  = ((wid >> 2) << 6) + lane;   // 0..127

    __shared__ float xrow[TT];         // 8 KB input row
    __shared__ float PPf[2][2048];     // 16 KB double-buffered partials:
                                       // [t&1][sel*1024 + q*256 + g*2 + (c&1)]
    __shared__ float yout[TT];         // 8 KB y buffer (no global ops in loop)

    // ---- prologue -------------------------------------------------------
    ((float4*)xrow)[tid] = ((const float4*)(input + (size_t)b * TT))[tid];

    // Rows 4idx..4idx+3. Row 450 = W_lin (y-row). Row >=451: clamp to 449
    // (junk partials stored but never read).
    const int r0 = 4 * idx;
#define ROWP(r) ((r) == H3 ? W_lin : W_hh + ((r) < H3 ? (r) : (H3 - 1)) * HH)
    const float* b0 = ROWP(r0)     + q;   // chain q: element k = 4m+q
    const float* b1 = ROWP(r0 + 1) + q;
    const float* b2 = ROWP(r0 + 2) + q;
    const float* b3 = ROWP(r0 + 3) + q;

    // m = 0..36 into explicit regs (A-pair rows (r0,r1) = v[100+2m],
    // B-pair rows (r2,r3) = v[176+2m]).
    asm volatile(
        LD4(100,101,176,177,0)    LD4(102,103,178,179,16)
        LD4(104,105,180,181,32)   LD4(106,107,182,183,48)
        LD4(108,109,184,185,64)   LD4(110,111,186,187,80)
        LD4(112,113,188,189,96)   LD4(114,115,190,191,112)
        LD4(116,117,192,193,128)  LD4(118,119,194,195,144)
        LD4(120,121,196,197,160)  LD4(122,123,198,199,176)
        LD4(124,125,200,201,192)  LD4(126,127,202,203,208)
        LD4(128,129,204,205,224)  LD4(130,131,206,207,240)
        LD4(132,133,208,209,256)  LD4(134,135,210,211,272)
        LD4(136,137,212,213,288)  LD4(138,139,214,215,304)
        LD4(140,141,216,217,320)  LD4(142,143,218,219,336)
        LD4(144,145,220,221,352)  LD4(146,147,222,223,368)
        LD4(148,149,224,225,384)  LD4(150,151,226,227,400)
        LD4(152,153,228,229,416)  LD4(154,155,230,231,432)
        LD4(156,157,232,233,448)  LD4(158,159,234,235,464)
        LD4(160,161,236,237,480)  LD4(162,163,238,239,496)
        LD4(164,165,240,241,512)  LD4(166,167,242,243,528)
        LD4(168,169,244,245,544)  LD4(170,171,246,247,560)
        LD4(172,173,248,249,576)
        "s_waitcnt vmcnt(0)\n\t"
        :
        : [b0] "v"(b0), [b1] "v"(b1), [b2] "v"(b2), [b3] "v"(b3)
        : WCLOB, "memory");
    // m = 37: k = 148+q. Real for q<2; for q>=2 h[150..151]=0 (exact, since
    // those hq lanes are never updated), so load in-bounds junk (k=144+q).
    {
        const int t37 = (q < 2) ? 148 : 144;
        float w0 = b0[t37], w1 = b1[t37], w2 = b2[t37], w3 = b3[t37];
        asm volatile(
            "v_mov_b32 v174, %0\n\tv_mov_b32 v175, %1\n\t"
            "v_mov_b32 v250, %2\n\tv_mov_b32 v251, %3\n\t"
            :: "v"(w0), "v"(w1), "v"(w2), "v"(w3)
            : "v174","v175","v250","v251");
    }

    // Phase-2 constants: lane l of chain-q wave owns hidden unit u = 4l+q.
    // Both waves sharing q (wid and wid+4) compute the same units redundantly
    // (bit-identical: same inputs, same code) so each wave owns its own hq.
    const int  u       = 4 * lane + q;
    const bool valid   = (lane < 38) && (u < HH);
    const bool ywriter = (wid == 0) && (lane == 38);   // idle lane does y-row
    float wih_r = 0.f, wih_z = 0.f, wih_n = 0.f;
    float bih_r = 0.f, bih_z = 0.f, bih_n = 0.f;
    float bhh_r = 0.f, bhh_z = 0.f, bhh_n = 0.f;
    if (valid) {
        wih_r = W_ih[u];          bih_r = b_ih[u];          bhh_r = b_hh[u];
        wih_z = W_ih[HH + u];     bih_z = b_ih[HH + u];     bhh_z = b_hh[HH + u];
        wih_n = W_ih[2 * HH + u]; bih_n = b_ih[2 * HH + u]; bhh_n = b_hh[2 * HH + u];
    }
    // Read indices within one PPf buffer for rows u, 150+u, 300+u
    // (chain offset +256 each).
    int ir = 0, iz = 0, in_ = 0;
    if (valid) {
        int r;
        r = u;          ir  = (((r & 3) >> 1) << 10) + ((r >> 2) << 1) + (r & 1);
        r = HH + u;     iz  = (((r & 3) >> 1) << 10) + ((r >> 2) << 1) + (r & 1);
        r = 2*HH + u;   in_ = (((r & 3) >> 1) << 10) + ((r >> 2) << 1) + (r & 1);
    }
    if (ywriter) {                        // alias the pr path to the y-row
        ir    = 1024 + (112 << 1);        // row 450: sel=1, g=112, bit0=0
        bhh_r = b_lin[0];                 // pr = sum4 + b_lin = y
    }

    float hq = 0.f;                       // lane l: h[4l+q]; h0 = 0
    float* outb = out + (size_t)b * TT;
    // Store pointers: float2 at 8B lane stride (conflict-free b64 writes).
    float2* st01 = (float2*)PPf + (q << 7) + idx;         // sel 0
    float2* st23 = (float2*)PPf + 512 + (q << 7) + idx;   // sel 1

    __syncthreads();

    // ---- recurrence -----------------------------------------------------
    // Iteration t dots h_{t-1}; row 450 gives y_{t-1}. Extra iteration
    // t==TT supplies y_{TT-1}; its h-update is guarded off.
    // ONE barrier per iteration: partials double-buffered on t&1.
    for (int t = 0; t <= TT; ++t) {
        const int sel = t & 1;
        float xt = xrow[t & (TT - 1)];    // broadcast read, hidden under asm

        // phase 1: chain a_q of rows r0..r3; hq is a live register from our
        // own phase-2 of iteration t-1 (no LDS read, no select).
        fx2 a01; a01.x = 0.f; a01.y = 0.f;
        fx2 a23; a23.x = 0.f; a23.y = 0.f;
        asm volatile(
            G4( 0, 1, 2, 3, "v[100:101]","v[176:177]", "v[102:103]","v[178:179]",
                            "v[104:105]","v[180:181]", "v[106:107]","v[182:183]")
            G4( 4, 5, 6, 7, "v[108:109]","v[184:185]", "v[110:111]","v[186:187]",
                            "v[112:113]","v[188:189]", "v[114:115]","v[190:191]")
            G4( 8, 9,10,11, "v[116:117]","v[192:193]", "v[118:119]","v[194:195]",
                            "v[120:121]","v[196:197]", "v[122:123]","v[198:199]")
            G4(12,13,14,15, "v[124:125]","v[200:201]", "v[126:127]","v[202:203]",
                            "v[128:129]","v[204:205]", "v[130:131]","v[206:207]")
            G4(16,17,18,19, "v[132:133]","v[208:209]", "v[134:135]","v[210:211]",
                            "v[136:137]","v[212:213]", "v[138:139]","v[214:215]")
            G4(20,21,22,23, "v[140:141]","v[216:217]", "v[142:143]","v[218:219]",
                            "v[144:145]","v[220:221]", "v[146:147]","v[222:223]")
            G4(24,25,26,27, "v[148:149]","v[224:225]", "v[150:151]","v[226:227]",
                            "v[152:153]","v[228:229]", "v[154:155]","v[230:231]")
            G4(28,29,30,31, "v[156:157]","v[232:233]", "v[158:159]","v[234:235]",
                            "v[160:161]","v[236:237]", "v[162:163]","v[238:239]")
            // last 6 k-elems: 6 readlanes up front, then 12 pk_fmas.
            "v_readlane_b32 s20, %[hq], 32\n\t"
            "v_readlane_b32 s22, %[hq], 33\n\t"
            "v_readlane_b32 s24, %[hq], 34\n\t"
            "v_readlane_b32 s26, %[hq], 35\n\t"
            "v_readlane_b32 s28, %[hq], 36\n\t"
            "v_readlane_b32 s30, %[hq], 37\n\t"
            PKB("s[20:21]", "v[164:165]", "%[a01]")
            PKB("s[20:21]", "v[240:241]", "%[a23]")
            PKB("s[22:23]", "v[166:167]", "%[a01]")
            PKB("s[22:23]", "v[242:243]", "%[a23]")
            PKB("s[24:25]", "v[168:169]", "%[a01]")
            PKB("s[24:25]", "v[244:245]", "%[a23]")
            PKB("s[26:27]", "v[170:171]", "%[a01]")
            PKB("s[26:27]", "v[246:247]", "%[a23]")
            PKB("s[28:29]", "v[172:173]", "%[a01]")
            PKB("s[28:29]", "v[248:249]", "%[a23]")
            PKB("s[30:31]", "v[174:175]", "%[a01]")
            PKB("s[30:31]", "v[250:251]", "%[a23]")
            : [a01] "+v"(a01), [a23] "+v"(a23)
            : [hq] "v"(hq)
            : "s20","s22","s24","s26","s28","s30", WCLOB);
        // Two conflict-free b64 stores (8B lane stride) into buffer t&1.
        float2 s0; s0.x = a01.x; s0.y = a01.y;
        float2 s1; s1.x = a23.x; s1.y = a23.y;
        *(st01 + (sel << 10)) = s0;
        *(st23 + (sel << 10)) = s1;
        __syncthreads();

        // phase 2: gates + hidden update, redundantly per wave (lanes 0..37).
        // pre_row = ((q0+q1)+(q2+q3)) + bhh -- same operands/tree as R12.
        // ywriter lane rides the same pr load shadow for the y-row.
        const float* pb = &PPf[0][0] + (sel << 11);
        if ((valid && t < TT) || ywriter) {
            float pr = ((pb[ir]        + pb[ir + 256])
                      + (pb[ir + 512]  + pb[ir + 768]))  + bhh_r;
            if (ywriter) {
                if (t > 0) yout[t - 1] = pr;
            } else {
                float pz = ((pb[iz]        + pb[iz + 256])
                          + (pb[iz + 512]  + pb[iz + 768]))  + bhh_z;
                float pn = ((pb[in_]       + pb[in_ + 256])
                          + (pb[in_ + 512] + pb[in_ + 768])) + bhh_n;
                float gr = fmaf(xt, wih_r, bih_r) + pr;
                float gz = fmaf(xt, wih_z, bih_z) + pz;
                float rr = 1.f / (1.f + __expf(-gr));
                float zz = 1.f / (1.f + __expf(-gz));
                float ta = fmaf(xt, wih_n, bih_n) + rr * pn;
                ta = fminf(fmaxf(ta, -15.f), 15.f);
                float e  = __expf(2.f * ta);
                float nn = (e - 1.f) / (e + 1.f);        // tanh
                float hnew = fmaf(zz, hq - nn, nn);      // (1-z)*n + z*h
                hq = fmaxf(hnew, 0.f);                   // relu
            }
        }
        // No second barrier: phase1(t+1) writes buffer (t+1)&1, and
        // barrier(t+1) fences all phase2(t) reads before phase1(t+2)
        // re-writes buffer t&1.
    }

    // ---- epilogue: coalesced y dump (the loop's only global write) -------
    __syncthreads();
    ((float4*)outb)[tid] = ((const float4*)yout)[tid];
}

extern "C" void kernel_launch(void* const* d_in, const int* in_sizes, int n_in,
                              void* d_out, int out_size, void* d_ws, size_t ws_size,
                              hipStream_t stream) {
    const float* input = (const float*)d_in[0];
    const float* W_ih  = (const float*)d_in[1];
    const float* W_hh  = (const float*)d_in[2];
    const float* b_ih  = (const float*)d_in[3];
    const float* b_hh  = (const float*)d_in[4];
    const float* W_lin = (const float*)d_in[5];
    const float* b_lin = (const float*)d_in[6];
    float* out = (float*)d_out;

    gru_seq_kernel<<<dim3(BB), dim3(512), 0, stream>>>(
        input, W_ih, W_hh, b_ih, b_hh, W_lin, b_lin, out);
}

// Round 3
// 1881.496 us; speedup vs baseline: 1.0584x; 1.0584x over previous
//
#include <hip/hip_runtime.h>
#include <math.h>

// B=256, T=2048, H=150. Sequential GRU, relu'd hidden, scalar linear head.
// 1 block / batch element (256 blocks = 256 CUs), 512 threads.
//
// R15 = R14 with the weight-load stride corrected. R14's LD8 used
// OFF=128*m (a x4 mis-scale of R12's 16B/slot pattern); chain w owns
// elements k=8m+w so the per-slot stride is 8 floats = 32 BYTES.
// Everything else verified by audit and unchanged from R14:
//   - wave w = chain (k == w mod 8), lane l = rows 8l..8l+7.
//   - readlanes halve vs R12: 38 -> 19 per wave; each feeds 4
//     broadcast-pk_fmas (chains a01/a23/a45/a67).
//   - h broadcast source: conflict-free hb[8][65] stride-4 b32 read.
//   - P2 8-term pairwise tree, threads 0..149; y-row via tid==450.
// Numerics: 8-chain re-association; absmax expected ~5e-4.

#define BB 256
#define TT 2048
#define HH 150
#define H3 450

typedef float fx2 __attribute__((ext_vector_type(2)));

// Clobber list for explicit weight registers v100..v251.
#define WCLOB \
  "v100","v101","v102","v103","v104","v105","v106","v107","v108","v109", \
  "v110","v111","v112","v113","v114","v115","v116","v117","v118","v119", \
  "v120","v121","v122","v123","v124","v125","v126","v127","v128","v129", \
  "v130","v131","v132","v133","v134","v135","v136","v137","v138","v139", \
  "v140","v141","v142","v143","v144","v145","v146","v147","v148","v149", \
  "v150","v151","v152","v153","v154","v155","v156","v157","v158","v159", \
  "v160","v161","v162","v163","v164","v165","v166","v167","v168","v169", \
  "v170","v171","v172","v173","v174","v175","v176","v177","v178","v179", \
  "v180","v181","v182","v183","v184","v185","v186","v187","v188","v189", \
  "v190","v191","v192","v193","v194","v195","v196","v197","v198","v199", \
  "v200","v201","v202","v203","v204","v205","v206","v207","v208","v209", \
  "v210","v211","v212","v213","v214","v215","v216","v217","v218","v219", \
  "v220","v221","v222","v223","v224","v225","v226","v227","v228","v229", \
  "v230","v231","v232","v233","v234","v235","v236","v237","v238","v239", \
  "v240","v241","v242","v243","v244","v245","v246","v247","v248","v249", \
  "v250","v251"

// Load one k-slot (slot m at byte offset 32*m) for all 8 rows.
#define LD8(a0,a1,b0,b1,c0,c1,d0,d1,OFF) \
  "global_load_dword v" #a0 ", %[p0], off offset:" #OFF "\n\t" \
  "global_load_dword v" #a1 ", %[p1], off offset:" #OFF "\n\t" \
  "global_load_dword v" #b0 ", %[p2], off offset:" #OFF "\n\t" \
  "global_load_dword v" #b1 ", %[p3], off offset:" #OFF "\n\t" \
  "global_load_dword v" #c0 ", %[p4], off offset:" #OFF "\n\t" \
  "global_load_dword v" #c1 ", %[p5], off offset:" #OFF "\n\t" \
  "global_load_dword v" #d0 ", %[p6], off offset:" #OFF "\n\t" \
  "global_load_dword v" #d1 ", %[p7], off offset:" #OFF "\n\t"

// pk_fma with src0-low broadcast to both packed lanes.
#define PKB(sp, vp, acc) \
  "v_pk_fma_f32 " acc ", " sp ", " vp ", " acc " op_sel:[0,0,0] op_sel_hi:[0,1,1]\n\t"

// 4 k-slots: 4 readlanes (even SGPRs) then 16 broadcast-pk_fmas (4 accum
// chains). First consumer of s20 is 4 insts after its write.
#define G4(m0,m1,m2,m3, A0,B0,C0,D0, A1,B1,C1,D1, A2,B2,C2,D2, A3,B3,C3,D3) \
  "v_readlane_b32 s20, %[hq], " #m0 "\n\t" \
  "v_readlane_b32 s22, %[hq], " #m1 "\n\t" \
  "v_readlane_b32 s24, %[hq], " #m2 "\n\t" \
  "v_readlane_b32 s26, %[hq], " #m3 "\n\t" \
  PKB("s[20:21]", A0, "%[a01]") PKB("s[20:21]", B0, "%[a23]") \
  PKB("s[20:21]", C0, "%[a45]") PKB("s[20:21]", D0, "%[a67]") \
  PKB("s[22:23]", A1, "%[a01]") PKB("s[22:23]", B1, "%[a23]") \
  PKB("s[22:23]", C1, "%[a45]") PKB("s[22:23]", D1, "%[a67]") \
  PKB("s[24:25]", A2, "%[a01]") PKB("s[24:25]", B2, "%[a23]") \
  PKB("s[24:25]", C2, "%[a45]") PKB("s[24:25]", D2, "%[a67]") \
  PKB("s[26:27]", A3, "%[a01]") PKB("s[26:27]", B3, "%[a23]") \
  PKB("s[26:27]", C3, "%[a45]") PKB("s[26:27]", D3, "%[a67]")

__global__ __launch_bounds__(512, 2) void gru_seq_kernel(
    const float* __restrict__ input,   // [B,T]
    const float* __restrict__ W_ih,    // [450,1]
    const float* __restrict__ W_hh,    // [450,150]
    const float* __restrict__ b_ih,    // [450]
    const float* __restrict__ b_hh,    // [450]
    const float* __restrict__ W_lin,   // [1,150]
    const float* __restrict__ b_lin,   // [1]
    float* __restrict__ out)           // [B,T]
{
    const int b    = blockIdx.x;
    const int tid  = threadIdx.x;
    const int lane = tid & 63;
    const int wid  = tid >> 6;               // 0..7 = chain (k mod 8)

    __shared__ float xrow[TT];         // 8 KB input row
    __shared__ float PPf[4160];        // 16.6 KB partials:
                                       // float2-idx = w*260 + p*65 + lane,
                                       // p = pair (rows 8l+2p, 8l+2p+1)
    __shared__ float hb[520];          // h swizzled: hb[(u&7)*65 + (u>>3)]
    __shared__ float yout[TT];         // 8 KB y buffer

    // ---- prologue -------------------------------------------------------
    ((float4*)xrow)[tid] = ((const float4*)(input + (size_t)b * TT))[tid];
    hb[tid < 512 ? tid : 0] = 0.f;     // tid covers 0..511
    if (tid < 8) hb[512 + tid] = 0.f;

    // Rows 8*lane..8*lane+7. Row 450 = W_lin (y-row). Row >=451: clamp to
    // 449 (junk partials stored but never read).
    const int r0 = 8 * lane;
#define ROWP(r) ((r) == H3 ? W_lin : W_hh + ((r) < H3 ? (r) : (H3 - 1)) * HH)
    const float* p0 = ROWP(r0)     + wid;   // chain w: element k = 8m+w
    const float* p1 = ROWP(r0 + 1) + wid;
    const float* p2 = ROWP(r0 + 2) + wid;
    const float* p3 = ROWP(r0 + 3) + wid;
    const float* p4 = ROWP(r0 + 4) + wid;
    const float* p5 = ROWP(r0 + 5) + wid;
    const float* p6 = ROWP(r0 + 6) + wid;
    const float* p7 = ROWP(r0 + 7) + wid;

    // m = 0..17 into explicit regs, slot m at byte offset 32*m. Pair-sets
    // (even-aligned): A rows (j0,j1) = v[100+2m], B (j2,j3) = v[138+2m],
    // C (j4,j5) = v[176+2m], D (j6,j7) = v[214+2m].
    asm volatile(
        LD8(100,101,138,139,176,177,214,215, 0)
        LD8(102,103,140,141,178,179,216,217, 32)
        LD8(104,105,142,143,180,181,218,219, 64)
        LD8(106,107,144,145,182,183,220,221, 96)
        LD8(108,109,146,147,184,185,222,223, 128)
        LD8(110,111,148,149,186,187,224,225, 160)
        LD8(112,113,150,151,188,189,226,227, 192)
        LD8(114,115,152,153,190,191,228,229, 224)
        LD8(116,117,154,155,192,193,230,231, 256)
        LD8(118,119,156,157,194,195,232,233, 288)
        LD8(120,121,158,159,196,197,234,235, 320)
        LD8(122,123,160,161,198,199,236,237, 352)
        LD8(124,125,162,163,200,201,238,239, 384)
        LD8(126,127,164,165,202,203,240,241, 416)
        LD8(128,129,166,167,204,205,242,243, 448)
        LD8(130,131,168,169,206,207,244,245, 480)
        LD8(132,133,170,171,208,209,246,247, 512)
        LD8(134,135,172,173,210,211,248,249, 544)
        "s_waitcnt vmcnt(0)\n\t"
        :
        : [p0] "v"(p0), [p1] "v"(p1), [p2] "v"(p2), [p3] "v"(p3),
          [p4] "v"(p4), [p5] "v"(p5), [p6] "v"(p6), [p7] "v"(p7)
        : WCLOB, "memory");
    // m = 18: k = 144+wid. Real for wid<6; for wid>=6 h[150..151]=0 forever
    // (hb slots never written), so load in-bounds junk (k=136+wid).
    {
        const int t18 = (wid < 6) ? 144 : 136;
        float w0 = p0[t18], w1 = p1[t18], w2 = p2[t18], w3 = p3[t18];
        float w4 = p4[t18], w5 = p5[t18], w6 = p6[t18], w7 = p7[t18];
        asm volatile(
            "v_mov_b32 v136, %0\n\tv_mov_b32 v137, %1\n\t"
            "v_mov_b32 v174, %2\n\tv_mov_b32 v175, %3\n\t"
            "v_mov_b32 v212, %4\n\tv_mov_b32 v213, %5\n\t"
            "v_mov_b32 v250, %6\n\tv_mov_b32 v251, %7\n\t"
            :: "v"(w0), "v"(w1), "v"(w2), "v"(w3),
               "v"(w4), "v"(w5), "v"(w6), "v"(w7)
            : "v136","v137","v174","v175","v212","v213","v250","v251");
    }

    // Phase-2 constants (threads 0..149) -- gate math verbatim from R12.
    float wih_r = 0.f, wih_z = 0.f, wih_n = 0.f;
    float bih_r = 0.f, bih_z = 0.f, bih_n = 0.f;
    float bhh_r = 0.f, bhh_z = 0.f, bhh_n = 0.f;
    if (tid < HH) {
        wih_r = W_ih[tid];          bih_r = b_ih[tid];          bhh_r = b_hh[tid];
        wih_z = W_ih[HH + tid];     bih_z = b_ih[HH + tid];     bhh_z = b_hh[HH + tid];
        wih_n = W_ih[2 * HH + tid]; bih_n = b_ih[2 * HH + tid]; bhh_n = b_hh[2 * HH + tid];
    }
    const float blin = b_lin[0];
    float hreg = 0.f;
    float* outb = out + (size_t)b * TT;
    // Store pointer: 4 float2 (8B lane stride = 2-way alias = free).
    float2* st = (float2*)PPf + wid * 260 + lane;
    // Phase-2 read indices: row r -> float idx (((r&7)>>1)*65 + (r>>3))*2
    // + (r&1); chain offset +520 floats each.
    int ir = 0, iz = 0, in_ = 0;
    if (tid < HH) {
        int r;
        r = tid;        ir  = (((r & 7) >> 1) * 65 + (r >> 3)) * 2 + (r & 1);
        r = HH + tid;   iz  = (((r & 7) >> 1) * 65 + (r >> 3)) * 2 + (r & 1);
        r = 2*HH + tid; in_ = (((r & 7) >> 1) * 65 + (r >> 3)) * 2 + (r & 1);
    }
    const int iy = (1 * 65 + 56) * 2;   // row 450: p=1, l=56, c=0 -> 242

    __syncthreads();

    // ---- recurrence -----------------------------------------------------
    // Iteration t dots h_{t-1}; row 450 gives y_{t-1}. Extra iteration
    // t==TT supplies y_{TT-1}; its h-update is guarded off.
    for (int t = 0; t <= TT; ++t) {
        // phase 1: chain w of rows 8l..8l+7. hq = hb[w][lane] = h[8*lane+w],
        // conflict-free stride-4 b32 read (no b128, no selects).
        float hq = hb[wid * 65 + lane];
        fx2 a01; a01.x = 0.f; a01.y = 0.f;
        fx2 a23; a23.x = 0.f; a23.y = 0.f;
        fx2 a45; a45.x = 0.f; a45.y = 0.f;
        fx2 a67; a67.x = 0.f; a67.y = 0.f;
        asm volatile(
            G4( 0, 1, 2, 3,
                "v[100:101]","v[138:139]","v[176:177]","v[214:215]",
                "v[102:103]","v[140:141]","v[178:179]","v[216:217]",
                "v[104:105]","v[142:143]","v[180:181]","v[218:219]",
                "v[106:107]","v[144:145]","v[182:183]","v[220:221]")
            G4( 4, 5, 6, 7,
                "v[108:109]","v[146:147]","v[184:185]","v[222:223]",
                "v[110:111]","v[148:149]","v[186:187]","v[224:225]",
                "v[112:113]","v[150:151]","v[188:189]","v[226:227]",
                "v[114:115]","v[152:153]","v[190:191]","v[228:229]")
            G4( 8, 9,10,11,
                "v[116:117]","v[154:155]","v[192:193]","v[230:231]",
                "v[118:119]","v[156:157]","v[194:195]","v[232:233]",
                "v[120:121]","v[158:159]","v[196:197]","v[234:235]",
                "v[122:123]","v[160:161]","v[198:199]","v[236:237]")
            G4(12,13,14,15,
                "v[124:125]","v[162:163]","v[200:201]","v[238:239]",
                "v[126:127]","v[164:165]","v[202:203]","v[240:241]",
                "v[128:129]","v[166:167]","v[204:205]","v[242:243]",
                "v[130:131]","v[168:169]","v[206:207]","v[244:245]")
            // tail: slots 16,17,18 -- 3 readlanes then 12 pk_fmas.
            "v_readlane_b32 s28, %[hq], 16\n\t"
            "v_readlane_b32 s30, %[hq], 17\n\t"
            "v_readlane_b32 s20, %[hq], 18\n\t"
            PKB("s[28:29]", "v[132:133]", "%[a01]")
            PKB("s[28:29]", "v[170:171]", "%[a23]")
            PKB("s[28:29]", "v[208:209]", "%[a45]")
            PKB("s[28:29]", "v[246:247]", "%[a67]")
            PKB("s[30:31]", "v[134:135]", "%[a01]")
            PKB("s[30:31]", "v[172:173]", "%[a23]")
            PKB("s[30:31]", "v[210:211]", "%[a45]")
            PKB("s[30:31]", "v[248:249]", "%[a67]")
            PKB("s[20:21]", "v[136:137]", "%[a01]")
            PKB("s[20:21]", "v[174:175]", "%[a23]")
            PKB("s[20:21]", "v[212:213]", "%[a45]")
            PKB("s[20:21]", "v[250:251]", "%[a67]")
            : [a01] "+v"(a01), [a23] "+v"(a23),
              [a45] "+v"(a45), [a67] "+v"(a67)
            : [hq] "v"(hq)
            : "s20","s22","s24","s26","s28","s30", WCLOB);
        // Four conflict-free b64 stores (8B lane stride).
        float2 s01; s01.x = a01.x; s01.y = a01.y;
        float2 s23; s23.x = a23.x; s23.y = a23.y;
        float2 s45; s45.x = a45.x; s45.y = a45.y;
        float2 s67; s67.x = a67.x; s67.y = a67.y;
        st[0]   = s01;
        st[65]  = s23;
        st[130] = s45;
        st[195] = s67;
        __syncthreads();

        // phase 2: gates + hidden update (threads 0..149), skipped at t==TT.
        // pre_row = (((c0+c1)+(c2+c3)) + ((c4+c5)+(c6+c7))) + bhh.
        if (t < TT && tid < HH) {
            float x  = xrow[t];
            float pr = (((PPf[ir]         + PPf[ir + 520])
                       + (PPf[ir + 1040]  + PPf[ir + 1560]))
                      + ((PPf[ir + 2080]  + PPf[ir + 2600])
                       + (PPf[ir + 3120]  + PPf[ir + 3640]))) + bhh_r;
            float pz = (((PPf[iz]         + PPf[iz + 520])
                       + (PPf[iz + 1040]  + PPf[iz + 1560]))
                      + ((PPf[iz + 2080]  + PPf[iz + 2600])
                       + (PPf[iz + 3120]  + PPf[iz + 3640]))) + bhh_z;
            float pn = (((PPf[in_]        + PPf[in_ + 520])
                       + (PPf[in_ + 1040] + PPf[in_ + 1560]))
                      + ((PPf[in_ + 2080] + PPf[in_ + 2600])
                       + (PPf[in_ + 3120] + PPf[in_ + 3640]))) + bhh_n;
            float gr = fmaf(x, wih_r, bih_r) + pr;
            float gz = fmaf(x, wih_z, bih_z) + pz;
            float r  = 1.f / (1.f + __expf(-gr));
            float z  = 1.f / (1.f + __expf(-gz));
            float ta = fmaf(x, wih_n, bih_n) + r * pn;
            ta = fminf(fmaxf(ta, -15.f), 15.f);
            float e  = __expf(2.f * ta);
            float n  = (e - 1.f) / (e + 1.f);        // tanh
            float hnew = fmaf(z, hreg - n, n);       // (1-z)*n + z*h
            hnew = fmaxf(hnew, 0.f);                 // relu
            hreg = hnew;
            hb[(tid & 7) * 65 + (tid >> 3)] = hnew;  // <=2-way write alias
        }
        // y_{t-1} from phase-1 row 450 (same 8-term tree), wave 7.
        if (t > 0 && tid == H3) {
            yout[t - 1] = (((PPf[iy]        + PPf[iy + 520])
                          + (PPf[iy + 1040] + PPf[iy + 1560]))
                         + ((PPf[iy + 2080] + PPf[iy + 2600])
                          + (PPf[iy + 3120] + PPf[iy + 3640]))) + blin;
        }
        __syncthreads();
    }

    // ---- epilogue: coalesced y dump (the loop's only global write) -------
    ((float4*)outb)[tid] = ((const float4*)yout)[tid];
}

extern "C" void kernel_launch(void* const* d_in, const int* in_sizes, int n_in,
                              void* d_out, int out_size, void* d_ws, size_t ws_size,
                              hipStream_t stream) {
    const float* input = (const float*)d_in[0];
    const float* W_ih  = (const float*)d_in[1];
    const float* W_hh  = (const float*)d_in[2];
    const float* b_ih  = (const float*)d_in[3];
    const float* b_hh  = (const float*)d_in[4];
    const float* W_lin = (const float*)d_in[5];
    const float* b_lin = (const float*)d_in[6];
    float* out = (float*)d_out;

    gru_seq_kernel<<<dim3(BB), dim3(512), 0, stream>>>(
        input, W_ih, W_hh, b_ih, b_hh, W_lin, b_lin, out);
}